// Round 1
// baseline (11974.484 us; speedup 1.0000x reference)
//
#include <hip/hip_runtime.h>
#include <math.h>

// Seq2Seq: 200-step LSTM encoder + 149-step greedy decoder, fp32, B=256.
// Multi-launch design (~650 kernels in the graph). All matmul phases use
// "j-parallel" layout: WG owns rows, lanes hold 4 batch cols of h^T,
// W read wave-uniform (scalar broadcast), K split over 4 waves + LDS reduce.

#define NB    256   // batch
#define SEQ   200
#define TSTEPS 150
#define HID   512
#define G4    2048  // 4*HID gate rows
#define VOC   231
#define EMBD  256
#define BVO   (NB*VOC)  // 59136

__device__ __forceinline__ float sigf(float x) { return 1.0f / (1.0f + expf(-x)); }

// ---------------- prep: fold FC into enc input weights, zero state ----------------
// grid 512x256 (131072 threads)
__global__ __launch_bounds__(256) void k_prep(
    const float* __restrict__ eWih, const float* __restrict__ fcW,
    const float* __restrict__ fcb,  const float* __restrict__ ebih,
    const float* __restrict__ ebhh, const int* __restrict__ target,
    float* __restrict__ wcomb, float* __restrict__ bcomb,
    float* __restrict__ hTA,   float* __restrict__ cET,
    int* __restrict__ token,   float* __restrict__ out)
{
  int tg = blockIdx.x * 256 + threadIdx.x;
  if (tg < G4) {
    const float* wr = eWih + tg * 256;   // enc_W_ih row (len 256)
    float s0 = 0.f, s1 = 0.f, sb = 0.f;
    for (int k = 0; k < 256; ++k) {
      float w = wr[k];
      s0 += w * fcW[2*k];
      s1 += w * fcW[2*k+1];
      sb += w * fcb[k];
    }
    wcomb[2*tg]   = s0;
    wcomb[2*tg+1] = s1;
    bcomb[tg]     = sb + ebih[tg] + ebhh[tg];
  }
  hTA[tg] = 0.f;           // h0 = 0 (h^T layout [k][b])
  cET[tg] = 0.f;           // enc c^T = 0
  if (tg < NB)  token[tg] = target[tg * TSTEPS];  // init_inp = target[:,0]
  if (tg < BVO) out[tg]   = 0.f;                  // outputs[0] = zeros
}

// ---------------- GIH[v][j] = emb[v] . dec_W_ih[j] + b_ih[j] + b_hh[j] ----------------
// grid 231x256
__global__ __launch_bounds__(256) void k_gih(
    const float* __restrict__ emb,  const float* __restrict__ dWih,
    const float* __restrict__ dbih, const float* __restrict__ dbhh,
    float* __restrict__ GIH)
{
  int v = blockIdx.x;
  __shared__ float e[EMBD];
  e[threadIdx.x] = emb[v * EMBD + threadIdx.x];
  __syncthreads();
  for (int u = 0; u < 8; ++u) {
    int j = u * 256 + threadIdx.x;
    const float* wr = dWih + j * EMBD;
    float s = 0.f;
#pragma unroll 4
    for (int k = 0; k < EMBD; k += 4) {
      float4 w4 = *(const float4*)(wr + k);
      s += e[k]*w4.x + e[k+1]*w4.y + e[k+2]*w4.z + e[k+3]*w4.w;
    }
    GIH[v * G4 + j] = s + dbih[j] + dbhh[j];
  }
}

// ---------------- encoder step: gates + pointwise fused ----------------
// grid 256x256. WG b owns k-pair {2*bid, 2*bid+1} x 4 gates = 8 W_hh rows.
__global__ __launch_bounds__(256) void k_enc(
    const float* __restrict__ hTin, float* __restrict__ hTout,
    float* __restrict__ cET,
    const float* __restrict__ Whh,  const float* __restrict__ wcomb,
    const float* __restrict__ bcomb,const float* __restrict__ train, int t)
{
  __shared__ float p[4][8][256];
  int tid = threadIdx.x;
  int q = tid >> 6, l = tid & 63;
  int k2 = blockIdx.x;
  const float* wp[8];
#pragma unroll
  for (int r = 0; r < 8; ++r) {
    int g = r & 3, kq = r >> 2;
    wp[r] = Whh + (g * 512 + 2 * k2 + kq) * 512;
  }
  float4 acc[8];
#pragma unroll
  for (int r = 0; r < 8; ++r) acc[r] = make_float4(0.f, 0.f, 0.f, 0.f);
  int kk0 = q * 128;
  for (int kk = kk0; kk < kk0 + 128; ++kk) {
    float4 h4 = *(const float4*)(hTin + kk * 256 + l * 4);
#pragma unroll
    for (int r = 0; r < 8; ++r) {
      float w = wp[r][kk];
      acc[r].x += w * h4.x; acc[r].y += w * h4.y;
      acc[r].z += w * h4.z; acc[r].w += w * h4.w;
    }
  }
#pragma unroll
  for (int r = 0; r < 8; ++r) *(float4*)&p[q][r][l * 4] = acc[r];
  __syncthreads();

  int b = tid;
  float x0 = train[(b * SEQ + t) * 2];
  float x1 = train[(b * SEQ + t) * 2 + 1];
#pragma unroll
  for (int u = 0; u < 2; ++u) {
    int k = 2 * k2 + u;
    float pre[4];
#pragma unroll
    for (int g = 0; g < 4; ++g) {
      int r = u * 4 + g;
      float s = p[0][r][b] + p[1][r][b] + p[2][r][b] + p[3][r][b];
      int j = g * 512 + k;
      pre[g] = s + wcomb[2*j] * x0 + wcomb[2*j+1] * x1 + bcomb[j];
    }
    float ii = sigf(pre[0]);
    float ff = sigf(pre[1]);
    float gg = tanhf(pre[2]);
    float oo = sigf(pre[3]);
    float c  = cET[k * 256 + b];
    float cn = ff * c + ii * gg;
    cET[k * 256 + b]   = cn;
    hTout[k * 256 + b] = oo * tanhf(cn);
  }
}

// ---------------- decoder X: GH = Whh.h  and  o1 = relu(W1.h + b1) ----------------
// grid 256x256, 10 rows per WG over 2560 = 2048 GH rows + 512 o1 rows.
#define RPW 10
__global__ __launch_bounds__(256) void k_x(
    const float* __restrict__ hTin,
    float* __restrict__ GHT, float* __restrict__ o1T,
    const float* __restrict__ dWhh,
    const float* __restrict__ W1, const float* __restrict__ b1)
{
  __shared__ float p[4][RPW][256];
  int tid = threadIdx.x, q = tid >> 6, l = tid & 63;
  int row0 = blockIdx.x * RPW;
  const float* wp[RPW];
#pragma unroll
  for (int r = 0; r < RPW; ++r) {
    int row = row0 + r;
    wp[r] = (row < G4) ? (dWhh + row * 512) : (W1 + (row - G4) * 512);
  }
  float4 acc[RPW];
#pragma unroll
  for (int r = 0; r < RPW; ++r) acc[r] = make_float4(0.f, 0.f, 0.f, 0.f);
  int kk0 = q * 128;
  for (int kk = kk0; kk < kk0 + 128; ++kk) {
    float4 h4 = *(const float4*)(hTin + kk * 256 + l * 4);
#pragma unroll
    for (int r = 0; r < RPW; ++r) {
      float w = wp[r][kk];
      acc[r].x += w * h4.x; acc[r].y += w * h4.y;
      acc[r].z += w * h4.z; acc[r].w += w * h4.w;
    }
  }
#pragma unroll
  for (int r = 0; r < RPW; ++r) *(float4*)&p[q][r][l * 4] = acc[r];
  __syncthreads();

  int b = tid;
#pragma unroll
  for (int u = 0; u < RPW; ++u) {
    int row = row0 + u;
    float s = p[0][u][b] + p[1][u][b] + p[2][u][b] + p[3][u][b];
    if (row < G4) {
      GHT[row * 256 + b] = s;
    } else {
      int jr = row - G4;
      o1T[jr * 256 + b] = fmaxf(s + b1[jr], 0.f);
    }
  }
}

// ---------------- decoder Y: o2 = relu(W2.o1 + b2), write output row ----------------
// grid 231x256
__global__ __launch_bounds__(256) void k_y(
    const float* __restrict__ o1T, float* __restrict__ o2T,
    const float* __restrict__ W2,  const float* __restrict__ b2,
    float* __restrict__ out, int rout)
{
  __shared__ float p[4][256];
  int tid = threadIdx.x, q = tid >> 6, l = tid & 63;
  int row = blockIdx.x;
  const float* wr = W2 + row * 512;
  float4 a = make_float4(0.f, 0.f, 0.f, 0.f);
  int kk0 = q * 128;
  for (int kk = kk0; kk < kk0 + 128; ++kk) {
    float4 h4 = *(const float4*)(o1T + kk * 256 + l * 4);
    float w = wr[kk];
    a.x += w * h4.x; a.y += w * h4.y; a.z += w * h4.z; a.w += w * h4.w;
  }
  *(float4*)&p[q][l * 4] = a;
  __syncthreads();
  int b = tid;
  float s = p[0][b] + p[1][b] + p[2][b] + p[3][b] + b2[row];
  s = fmaxf(s, 0.f);
  o2T[row * 256 + b] = s;
  out[(size_t)rout * BVO + b * VOC + row] = s;
}

// ---------------- decoder Z: argmax(o2) -> token; LSTM pointwise -> h_next ----------------
// grid 256x256, WG = one batch item.
__global__ __launch_bounds__(256) void k_z(
    const float* __restrict__ o2T, const float* __restrict__ GHT,
    const float* __restrict__ GIH,
    const float* __restrict__ cET, float* __restrict__ cD,
    float* __restrict__ hTout, const int* __restrict__ token, int first)
{
  __shared__ float mv[256];
  __shared__ int   mi[256];
  int b = blockIdx.x, i = threadIdx.x;
  int tok;
  if (!first) {
    mv[i] = (i < VOC) ? o2T[i * 256 + b] : -1e30f;
    mi[i] = i;
    __syncthreads();
    for (int off = 128; off > 0; off >>= 1) {
      if (i < off) {
        float vo = mv[i + off]; int io = mi[i + off];
        // numpy argmax: first occurrence of max
        if (vo > mv[i] || (vo == mv[i] && io < mi[i])) { mv[i] = vo; mi[i] = io; }
      }
      __syncthreads();
    }
    tok = mi[0];
  } else {
    tok = token[b];
  }
  const float* gr = GIH + tok * G4;
#pragma unroll
  for (int u = 0; u < 2; ++u) {
    int k = u * 256 + i;
    float pre[4];
#pragma unroll
    for (int g = 0; g < 4; ++g) {
      int j = g * 512 + k;
      pre[g] = GHT[j * 256 + b] + gr[j];
    }
    float ii = sigf(pre[0]);
    float ff = sigf(pre[1]);
    float gg = tanhf(pre[2]);
    float oo = sigf(pre[3]);
    float c  = first ? cET[k * 256 + b] : cD[b * 512 + k];
    float cn = ff * c + ii * gg;
    cD[b * 512 + k]    = cn;
    hTout[k * 256 + b] = oo * tanhf(cn);
  }
}

extern "C" void kernel_launch(void* const* d_in, const int* in_sizes, int n_in,
                              void* d_out, int out_size, void* d_ws, size_t ws_size,
                              hipStream_t stream) {
  const float* train = (const float*)d_in[0];
  const int*   target= (const int*)  d_in[1];
  const float* fcW   = (const float*)d_in[2];
  const float* fcb   = (const float*)d_in[3];
  const float* eWih  = (const float*)d_in[4];
  const float* eWhh  = (const float*)d_in[5];
  const float* ebih  = (const float*)d_in[6];
  const float* ebhh  = (const float*)d_in[7];
  const float* emb   = (const float*)d_in[8];
  const float* dWih  = (const float*)d_in[9];
  const float* dWhh  = (const float*)d_in[10];
  const float* dbih  = (const float*)d_in[11];
  const float* dbhh  = (const float*)d_in[12];
  const float* W1    = (const float*)d_in[13];
  const float* b1    = (const float*)d_in[14];
  const float* W2    = (const float*)d_in[15];
  const float* b2    = (const float*)d_in[16];
  float* out = (float*)d_out;

  float* ws   = (float*)d_ws;
  float* wcomb = ws;                    // 4096
  float* bcomb = wcomb + 4096;          // 2048
  float* GIH   = bcomb + 2048;          // 473088
  float* hTA   = GIH + 473088;          // 131072
  float* hTB   = hTA + 131072;          // 131072
  float* cET   = hTB + 131072;          // 131072
  float* cD    = cET + 131072;          // 131072
  float* o1T   = cD  + 131072;          // 131072
  float* o2T   = o1T + 131072;          // 59136
  float* GHT   = o2T + 59136;           // 524288
  int*   token = (int*)(GHT + 524288);  // 256
  size_t need = (size_t)((token + 256) - (int*)ws) * sizeof(int);
  if (ws_size < need) return;  // workspace too small: fail visibly

  k_prep<<<512, 256, 0, stream>>>(eWih, fcW, fcb, ebih, ebhh, target,
                                  wcomb, bcomb, hTA, cET, token, out);
  k_gih<<<VOC, 256, 0, stream>>>(emb, dWih, dbih, dbhh, GIH);

  // encoder: t even reads hTA->hTB, t odd reads hTB->hTA. Final h in hTA.
  for (int t = 0; t < SEQ; ++t) {
    const float* hin = (t & 1) ? hTB : hTA;
    float* hout      = (t & 1) ? hTA : hTB;
    k_enc<<<256, 256, 0, stream>>>(hin, hout, cET, eWhh, wcomb, bcomb, train, t);
  }

  // decoder bootstrap: GH(h_enc), then pointwise with token0 -> h_1 (in hTB)
  k_x<<<256, 256, 0, stream>>>(hTA, GHT, o1T, dWhh, W1, b1);
  k_z<<<256, 256, 0, stream>>>(o2T, GHT, GIH, cET, cD, hTB, token, 1);

  // decoder steps s=0..148: X(h_{s+1}) -> Y(out row s+1) -> Z(-> h_{s+2})
  for (int s = 0; s < TSTEPS - 1; ++s) {
    const float* hin = (s & 1) ? hTA : hTB;
    float* hout      = (s & 1) ? hTB : hTA;
    k_x<<<256, 256, 0, stream>>>(hin, GHT, o1T, dWhh, W1, b1);
    k_y<<<VOC, 256, 0, stream>>>(o1T, o2T, W2, b2, out, s + 1);
    if (s < TSTEPS - 2)
      k_z<<<256, 256, 0, stream>>>(o2T, GHT, GIH, cD, cD, hout, token, 0);
  }
}